// Round 2
// baseline (2133.348 us; speedup 1.0000x reference)
//
#include <hip/hip_runtime.h>
#include <hip/hip_bf16.h>
#include <stdint.h>

#define B_ 4096
#define L_ 128
#define I_ 64
#define H_ 256
#define D_ 32
#define T_ 101
#define K_ 320   // I_+H_
#define NG 1024  // 4*H_

typedef __attribute__((ext_vector_type(8))) short short8;
typedef __attribute__((ext_vector_type(4))) float f32x4;

__device__ __forceinline__ void gload16(const void* g, const void* l) {
  __builtin_amdgcn_global_load_lds(
      (const __attribute__((address_space(1))) void*)(uintptr_t)g,
      (__attribute__((address_space(3))) void*)(uintptr_t)l, 16, 0, 0);
}

__device__ __forceinline__ float sigf(float x) { return 1.0f / (1.0f + __expf(-x)); }
__device__ __forceinline__ float tanhf_(float x) { return 2.0f / (1.0f + __expf(-2.0f * x)) - 1.0f; }

// ---------------- prep: build interleaved combined weight (bf16) + bias ----------------
// column mapping: n = (u&15) | (g<<4) | ((u>>4)<<6)  ->  orig row r = g*256 + u
__global__ void prep_w(const float* __restrict__ W_ih, const float* __restrict__ W_hh,
                       const float* __restrict__ b_ih, const float* __restrict__ b_hh,
                       __hip_bfloat16* __restrict__ Wc, float* __restrict__ bc) {
  int idx = blockIdx.x * 256 + threadIdx.x;
  if (idx < NG * K_) {
    int n = idx / K_, k = idx % K_;
    int g = (n >> 4) & 3;
    int u = (n & 15) | ((n >> 6) << 4);
    int r = g * H_ + u;
    float v = (k < I_) ? W_ih[r * I_ + k] : W_hh[r * H_ + (k - I_)];
    Wc[idx] = __float2bfloat16(v);
  }
  if (idx < NG) {
    int n = idx;
    int g = (n >> 4) & 3;
    int u = (n & 15) | ((n >> 6) << 4);
    int r = g * H_ + u;
    bc[n] = b_ih[r] + b_hh[r];
  }
}

// ---------------- prep: transpose input_seq [B,L,I] f32 -> xT [L,B,I] bf16 ----------------
__global__ void prep_x(const float* __restrict__ x, __hip_bfloat16* __restrict__ xT) {
  int l = blockIdx.x;
  int b = blockIdx.y * 4 + threadIdx.y;
  int i = threadIdx.x;
  xT[((size_t)l * B_ + b) * I_ + i] = __float2bfloat16(x[((size_t)b * L_ + l) * I_ + i]);
}

// ---------------- prep: zero h0 (bf16) and c (f32) ----------------
__global__ void prep_zero(__hip_bfloat16* __restrict__ h0, float* __restrict__ c) {
  int idx = blockIdx.x * 256 + threadIdx.x;
  if (idx < B_ * H_) {
    h0[idx] = __float2bfloat16(0.0f);
    c[idx] = 0.0f;
  }
}

// ---------------- LSTM step: gates GEMM (M=4096,N=1024 interleaved,K=320) + pointwise ----
// grid (16,32): blockIdx.x -> 64 gate-cols (=16 units), blockIdx.y -> 128 batch rows
__global__ __launch_bounds__(256) void lstm_step(
    const __hip_bfloat16* __restrict__ x_t,   // [B,64]
    const __hip_bfloat16* __restrict__ h_in,  // [B,256]
    __hip_bfloat16* __restrict__ h_out,       // [B,256]
    const __hip_bfloat16* __restrict__ Wc,    // [1024,320]
    const float* __restrict__ bc,             // [1024]
    float* __restrict__ c)                    // [B,256]
{
  __shared__ __hip_bfloat16 As[128 * 32];  // [row][k] 64B rows, chunk-swizzled
  __shared__ __hip_bfloat16 Bs[64 * 32];

  const int tid = threadIdx.x;
  const int lane = tid & 63;
  const int wid = tid >> 6;          // 4 waves, wave w owns rows [w*32, w*32+32)
  const int n0 = blockIdx.x * 64;
  const int b0 = blockIdx.y * 128;

  f32x4 acc[2][4];
  #pragma unroll
  for (int mi = 0; mi < 2; ++mi)
    #pragma unroll
    for (int ni = 0; ni < 4; ++ni)
      #pragma unroll
      for (int j = 0; j < 4; ++j) acc[mi][ni][j] = 0.0f;

  const int sr = lane >> 2;  // staging row-within-16
  const int sc = lane & 3;   // staging chunk

  #pragma unroll
  for (int kk = 0; kk < 10; ++kk) {
    const int k0 = kk * 32;
    // stage A (128x32 bf16 = 8KB): 2 calls/wave, rows [wid*32, +32)
    #pragma unroll
    for (int ca = 0; ca < 2; ++ca) {
      const int r = wid * 32 + ca * 16 + sr;
      const int ch = sc ^ (r & 3);  // pre-swizzled source chunk
      const char* src;
      if (k0 < I_)
        src = (const char*)x_t + (((size_t)(b0 + r)) * I_ + (k0 + ch * 8)) * 2;
      else
        src = (const char*)h_in + (((size_t)(b0 + r)) * H_ + (k0 - I_ + ch * 8)) * 2;
      gload16(src, (const char*)As + (wid * 32 + ca * 16) * 64);
    }
    // stage B (64x32 bf16 = 4KB): 1 call/wave, rows [wid*16, +16)
    {
      const int r = wid * 16 + sr;
      const int ch = sc ^ (r & 3);
      const char* src = (const char*)Wc + (((size_t)(n0 + r)) * K_ + (k0 + ch * 8)) * 2;
      gload16(src, (const char*)Bs + (wid * 16) * 64);
    }
    __syncthreads();

    short8 av[2], bv[4];
    #pragma unroll
    for (int mi = 0; mi < 2; ++mi) {
      const int rr = wid * 32 + mi * 16 + (lane & 15);
      const int ch = (lane >> 4) ^ (rr & 3);
      av[mi] = *(const short8*)((const char*)As + rr * 64 + ch * 16);
    }
    #pragma unroll
    for (int ni = 0; ni < 4; ++ni) {
      const int rr = ni * 16 + (lane & 15);
      const int ch = (lane >> 4) ^ (rr & 3);
      bv[ni] = *(const short8*)((const char*)Bs + rr * 64 + ch * 16);
    }
    #pragma unroll
    for (int mi = 0; mi < 2; ++mi)
      #pragma unroll
      for (int ni = 0; ni < 4; ++ni)
        acc[mi][ni] = __builtin_amdgcn_mfma_f32_16x16x32_bf16(av[mi], bv[ni], acc[mi][ni], 0, 0, 0);
    __syncthreads();
  }

  // epilogue: lane's 4 ni-frags are gates i,f,g,o of unit u — no cross-lane needed
  const int u = blockIdx.x * 16 + (lane & 15);
  const int colb = lane & 15;
  const float bi = bc[n0 + colb];
  const float bf2 = bc[n0 + 16 + colb];
  const float bg = bc[n0 + 32 + colb];
  const float bo = bc[n0 + 48 + colb];
  #pragma unroll
  for (int mi = 0; mi < 2; ++mi) {
    #pragma unroll
    for (int r = 0; r < 4; ++r) {
      const int row = b0 + wid * 32 + mi * 16 + (lane >> 4) * 4 + r;
      const float iv = sigf(acc[mi][0][r] + bi);
      const float fv = sigf(acc[mi][1][r] + bf2);
      const float gv = tanhf_(acc[mi][2][r] + bg);
      const float ov = sigf(acc[mi][3][r] + bo);
      float cc = c[(size_t)row * H_ + u];
      cc = fv * cc + iv * gv;
      c[(size_t)row * H_ + u] = cc;
      h_out[(size_t)row * H_ + u] = __float2bfloat16(ov * tanhf_(cc));
    }
  }
}

// ---------------- hid projections: f_hid/g_hid = hid @ W[:, :256]^T + b ----------------
__global__ __launch_bounds__(256) void hid_proj(
    const __hip_bfloat16* __restrict__ h, const float* __restrict__ drift_W,
    const float* __restrict__ drift_b, const float* __restrict__ diff_W,
    const float* __restrict__ diff_b, float* __restrict__ fhid, float* __restrict__ ghid) {
  __shared__ float WdL[H_ * D_];  // [k][d], transposed for conflict-free reads
  __shared__ float WgL[H_ * D_];
  for (int idx = threadIdx.x; idx < H_ * D_; idx += 256) {
    int k = idx >> 5, d = idx & 31;
    WdL[idx] = drift_W[d * (H_ + D_) + k];
    WgL[idx] = diff_W[d * (H_ + D_) + k];
  }
  __syncthreads();
  const int row = blockIdx.x * 8 + (threadIdx.x >> 5);
  const int d = threadIdx.x & 31;
  const __hip_bfloat16* hr = h + (size_t)row * H_;
  float f = drift_b[d], g = diff_b[d];
  for (int k = 0; k < H_; ++k) {
    float hv = __bfloat162float(hr[k]);
    f += hv * WdL[k * 32 + d];
    g += hv * WgL[k * 32 + d];
  }
  fhid[(size_t)row * D_ + d] = f;
  ghid[(size_t)row * D_ + d] = g;
}

// ---------------- SDE Euler-Maruyama: whole 100-step loop, y in registers ----------------
__global__ __launch_bounds__(256) void sde_kernel(
    const float* __restrict__ ts, const float* __restrict__ y0, const float* __restrict__ dW,
    const float* __restrict__ drift_W, const float* __restrict__ diff_W,
    const float* __restrict__ fhid, const float* __restrict__ ghid, float* __restrict__ out) {
  const int g = blockIdx.x * 256 + threadIdx.x;  // b*32+d
  const int d = g & 31;
  float A[32], G[32];
  #pragma unroll
  for (int k = 0; k < 32; ++k) {
    A[k] = drift_W[d * (H_ + D_) + H_ + k];
    G[k] = diff_W[d * (H_ + D_) + H_ + k];
  }
  float y = y0[g];
  const float fh = fhid[g], gh = ghid[g];
  out[g] = y;  // t=0 slice
  for (int t = 0; t < T_ - 1; ++t) {
    const float dt = ts[t + 1] - ts[t];
    const float sdt = sqrtf(dt);
    float f = fh, gg = gh;
    #pragma unroll
    for (int k = 0; k < 32; ++k) {
      const float yk = __shfl(y, k, 32);
      f += A[k] * yk;
      gg += G[k] * yk;
    }
    const float dw = dW[(size_t)t * (B_ * D_) + g];
    y = y + f * dt + gg * (dw * sdt);
    out[(size_t)(t + 1) * (B_ * D_) + g] = y;
  }
}

extern "C" void kernel_launch(void* const* d_in, const int* in_sizes, int n_in,
                              void* d_out, int out_size, void* d_ws, size_t ws_size,
                              hipStream_t stream) {
  const float* ts = (const float*)d_in[0];
  const float* y0 = (const float*)d_in[1];
  const float* xseq = (const float*)d_in[2];
  const float* dW = (const float*)d_in[3];
  const float* W_ih = (const float*)d_in[4];
  const float* W_hh = (const float*)d_in[5];
  const float* b_ih = (const float*)d_in[6];
  const float* b_hh = (const float*)d_in[7];
  const float* drift_W = (const float*)d_in[8];
  const float* drift_b = (const float*)d_in[9];
  const float* diff_W = (const float*)d_in[10];
  const float* diff_b = (const float*)d_in[11];
  float* out = (float*)d_out;

  char* p = (char*)d_ws;
  __hip_bfloat16* xT = (__hip_bfloat16*)p; p += (size_t)L_ * B_ * I_ * 2;  // 67.1 MB
  __hip_bfloat16* Wc = (__hip_bfloat16*)p; p += (size_t)NG * K_ * 2;       // 655 KB
  float* bc = (float*)p;                   p += (size_t)NG * 4;
  __hip_bfloat16* h0 = (__hip_bfloat16*)p; p += (size_t)B_ * H_ * 2;
  __hip_bfloat16* h1 = (__hip_bfloat16*)p; p += (size_t)B_ * H_ * 2;
  float* c = (float*)p;                    p += (size_t)B_ * H_ * 4;
  float* fh = (float*)p;                   p += (size_t)B_ * D_ * 4;
  float* gh = (float*)p;                   p += (size_t)B_ * D_ * 4;

  prep_w<<<(NG * K_ + 255) / 256, 256, 0, stream>>>(W_ih, W_hh, b_ih, b_hh, Wc, bc);
  prep_x<<<dim3(L_, B_ / 4), dim3(64, 4), 0, stream>>>(xseq, xT);
  prep_zero<<<(B_ * H_ + 255) / 256, 256, 0, stream>>>(h0, c);

  __hip_bfloat16* hb[2] = {h0, h1};
  for (int t = 0; t < L_; ++t) {
    lstm_step<<<dim3(16, 32), 256, 0, stream>>>(xT + (size_t)t * B_ * I_, hb[t & 1],
                                                hb[(t + 1) & 1], Wc, bc, c);
  }
  hid_proj<<<B_ / 8, 256, 0, stream>>>(hb[L_ & 1], drift_W, drift_b, diff_W, diff_b, fh, gh);
  sde_kernel<<<(B_ * D_) / 256, 256, 0, stream>>>(ts, y0, dW, drift_W, diff_W, fh, gh, out);
}

// Round 3
// 1321.482 us; speedup vs baseline: 1.6144x; 1.6144x over previous
//
#include <hip/hip_runtime.h>
#include <hip/hip_bf16.h>
#include <stdint.h>

#define B_ 4096
#define L_ 128
#define I_ 64
#define H_ 256
#define D_ 32
#define T_ 101
#define K_ 320   // I_+H_
#define NG 1024  // 4*H_

typedef __attribute__((ext_vector_type(8))) short short8;
typedef __attribute__((ext_vector_type(4))) float f32x4;

__device__ __forceinline__ void gload16(const void* g, const void* l) {
  __builtin_amdgcn_global_load_lds(
      (const __attribute__((address_space(1))) void*)(uintptr_t)g,
      (__attribute__((address_space(3))) void*)(uintptr_t)l, 16, 0, 0);
}

__device__ __forceinline__ float sigf(float x) { return 1.0f / (1.0f + __expf(-x)); }
__device__ __forceinline__ float tanhf_(float x) { return 2.0f / (1.0f + __expf(-2.0f * x)) - 1.0f; }

// ---------------- prep: build interleaved combined weight (bf16) + bias ----------------
// column mapping: n = (u&15) | (g<<4) | ((u>>4)<<6)  ->  orig row r = g*256 + u
__global__ void prep_w(const float* __restrict__ W_ih, const float* __restrict__ W_hh,
                       const float* __restrict__ b_ih, const float* __restrict__ b_hh,
                       __hip_bfloat16* __restrict__ Wc, float* __restrict__ bc) {
  int idx = blockIdx.x * 256 + threadIdx.x;
  if (idx < NG * K_) {
    int n = idx / K_, k = idx % K_;
    int g = (n >> 4) & 3;
    int u = (n & 15) | ((n >> 6) << 4);
    int r = g * H_ + u;
    float v = (k < I_) ? W_ih[r * I_ + k] : W_hh[r * H_ + (k - I_)];
    Wc[idx] = __float2bfloat16(v);
  }
  if (idx < NG) {
    int n = idx;
    int g = (n >> 4) & 3;
    int u = (n & 15) | ((n >> 6) << 4);
    int r = g * H_ + u;
    bc[n] = b_ih[r] + b_hh[r];
  }
}

// ---------------- prep: transpose input_seq [B,L,I] f32 -> xT [L,B,I] bf16 ----------------
__global__ void prep_x(const float* __restrict__ x, __hip_bfloat16* __restrict__ xT) {
  int l = blockIdx.x;
  int b = blockIdx.y * 4 + threadIdx.y;
  int i = threadIdx.x;
  xT[((size_t)l * B_ + b) * I_ + i] = __float2bfloat16(x[((size_t)b * L_ + l) * I_ + i]);
}

// ---------------- prep: zero h0 (bf16) and c (f32) ----------------
__global__ void prep_zero(__hip_bfloat16* __restrict__ h0, float* __restrict__ c) {
  int idx = blockIdx.x * 256 + threadIdx.x;
  if (idx < B_ * H_) {
    h0[idx] = __float2bfloat16(0.0f);
    c[idx] = 0.0f;
  }
}

// ---------------- LSTM step v2: 128x128 tile, BK=64, dbuf 2-phase, XCD-grouped ----------
// grid 256 x 512 threads. 8 waves: wm = wid&3 (rows wm*32), wn = wid>>2 (cols wn*64).
__global__ __launch_bounds__(512) void lstm_step2(
    const __hip_bfloat16* __restrict__ x_t,   // [B,64]
    const __hip_bfloat16* __restrict__ h_in,  // [B,256]
    __hip_bfloat16* __restrict__ h_out,       // [B,256]
    const __hip_bfloat16* __restrict__ Wc,    // [1024,320]
    const float* __restrict__ bc,             // [1024]
    float* __restrict__ c)                    // [B,256]
{
  __shared__ __hip_bfloat16 As[2][128 * 64];  // [row][k] 128B rows, chunk-XOR-swizzled
  __shared__ __hip_bfloat16 Bs[2][128 * 64];

  const int tid = threadIdx.x;
  const int lane = tid & 63;
  const int wid = tid >> 6;       // 0..7
  const int wm = wid & 3;         // row-wave 0..3 (32 rows each)
  const int wn = wid >> 2;        // col-wave 0..1 (64 cols each)

  // XCD-bijective swizzle: all 8 n-blocks of a b-group land on one XCD (flat%8).
  const int flat = blockIdx.x;
  const int xcd = flat & 7, slot = flat >> 3;     // slot 0..31
  const int b_idx = xcd * 4 + (slot >> 3);        // 0..31
  const int n_idx = slot & 7;                     // 0..7
  const int b0 = b_idx * 128, n0 = n_idx * 128;

  const int colb = lane & 15;

  // accumulators initialized with bias (same value for the 4 row-regs of a frag)
  f32x4 acc[2][4];
  #pragma unroll
  for (int ni = 0; ni < 4; ++ni) {
    const float bv = bc[n0 + wn * 64 + ni * 16 + colb];
    #pragma unroll
    for (int mi = 0; mi < 2; ++mi)
      #pragma unroll
      for (int j = 0; j < 4; ++j) acc[mi][ni][j] = bv;
  }

  const int sr8 = lane >> 3;           // row-within-8 for staging
  const int sch = lane & 7;            // dest chunk
  const int srcch = sch ^ sr8;         // source chunk (XOR involution, r&7 == sr8)

  // stage K-chunk kk (BK=64) into buffer buf: A(16KB) + B(16KB), 2 gload16 each
  #define STAGE(kk, buf)                                                             \
    {                                                                                \
      _Pragma("unroll")                                                              \
      for (int c2 = 0; c2 < 2; ++c2) {                                               \
        const int r = (c2 * 8 + wid) * 8 + sr8;                                      \
        const char* srcA;                                                            \
        if ((kk) == 0)                                                               \
          srcA = (const char*)x_t + (((size_t)(b0 + r)) * I_ + srcch * 8) * 2;       \
        else                                                                         \
          srcA = (const char*)h_in +                                                 \
                 (((size_t)(b0 + r)) * H_ + ((kk)*64 - 64) + srcch * 8) * 2;         \
        gload16(srcA, (const char*)As[buf] + (c2 * 8 + wid) * 1024);                 \
        const char* srcB = (const char*)Wc +                                         \
                           (((size_t)(n0 + r)) * K_ + (kk)*64 + srcch * 8) * 2;      \
        gload16(srcB, (const char*)Bs[buf] + (c2 * 8 + wid) * 1024);                 \
      }                                                                              \
    }

  STAGE(0, 0);
  __syncthreads();

  #pragma unroll
  for (int kk = 0; kk < 5; ++kk) {
    const int cur = kk & 1;
    if (kk < 4) STAGE(kk + 1, cur ^ 1);  // issue next-tile loads BEFORE compute

    const char* Ab = (const char*)As[cur];
    const char* Bb = (const char*)Bs[cur];
    short8 av[2][2], bv[2][4];
    #pragma unroll
    for (int ks = 0; ks < 2; ++ks) {
      const int cc = ks * 4 + (lane >> 4);
      #pragma unroll
      for (int mi = 0; mi < 2; ++mi) {
        const int rr = wm * 32 + mi * 16 + colb;
        av[ks][mi] = *(const short8*)(Ab + rr * 128 + (cc ^ (rr & 7)) * 16);
      }
      #pragma unroll
      for (int ni = 0; ni < 4; ++ni) {
        const int rr = wn * 64 + ni * 16 + colb;
        bv[ks][ni] = *(const short8*)(Bb + rr * 128 + (cc ^ (rr & 7)) * 16);
      }
    }
    #pragma unroll
    for (int ks = 0; ks < 2; ++ks)
      #pragma unroll
      for (int mi = 0; mi < 2; ++mi)
        #pragma unroll
        for (int ni = 0; ni < 4; ++ni)
          acc[mi][ni] =
              __builtin_amdgcn_mfma_f32_16x16x32_bf16(av[ks][mi], bv[ks][ni], acc[mi][ni], 0, 0, 0);
    __syncthreads();  // drains vmcnt (next tile) + lgkm; loads had whole compute to fly
  }

  // epilogue: ni = gate (i,f,g,o) of unit u; bias already in acc
  const int u = 32 * n_idx + 16 * wn + colb;
  #pragma unroll
  for (int mi = 0; mi < 2; ++mi) {
    #pragma unroll
    for (int r = 0; r < 4; ++r) {
      const int row = b0 + wm * 32 + mi * 16 + (lane >> 4) * 4 + r;
      const float iv = sigf(acc[mi][0][r]);
      const float fv = sigf(acc[mi][1][r]);
      const float gv = tanhf_(acc[mi][2][r]);
      const float ov = sigf(acc[mi][3][r]);
      float cc = c[(size_t)row * H_ + u];
      cc = fv * cc + iv * gv;
      c[(size_t)row * H_ + u] = cc;
      h_out[(size_t)row * H_ + u] = __float2bfloat16(ov * tanhf_(cc));
    }
  }
  #undef STAGE
}

// ---------------- hid projections: f_hid/g_hid = hid @ W[:, :256]^T + b ----------------
__global__ __launch_bounds__(256) void hid_proj(
    const __hip_bfloat16* __restrict__ h, const float* __restrict__ drift_W,
    const float* __restrict__ drift_b, const float* __restrict__ diff_W,
    const float* __restrict__ diff_b, float* __restrict__ fhid, float* __restrict__ ghid) {
  __shared__ float WdL[H_ * D_];  // [k][d]
  __shared__ float WgL[H_ * D_];
  for (int idx = threadIdx.x; idx < H_ * D_; idx += 256) {
    int k = idx >> 5, d = idx & 31;
    WdL[idx] = drift_W[d * (H_ + D_) + k];
    WgL[idx] = diff_W[d * (H_ + D_) + k];
  }
  __syncthreads();
  const int row = blockIdx.x * 8 + (threadIdx.x >> 5);
  const int d = threadIdx.x & 31;
  const __hip_bfloat16* hr = h + (size_t)row * H_;
  float f = drift_b[d], g = diff_b[d];
  for (int k = 0; k < H_; ++k) {
    float hv = __bfloat162float(hr[k]);
    f += hv * WdL[k * 32 + d];
    g += hv * WgL[k * 32 + d];
  }
  fhid[(size_t)row * D_ + d] = f;
  ghid[(size_t)row * D_ + d] = g;
}

// ---------------- SDE Euler-Maruyama: depth-2 dW prefetch, 4-way split accumulators ----
__global__ __launch_bounds__(256) void sde_kernel(
    const float* __restrict__ ts, const float* __restrict__ y0, const float* __restrict__ dW,
    const float* __restrict__ drift_W, const float* __restrict__ diff_W,
    const float* __restrict__ fhid, const float* __restrict__ ghid, float* __restrict__ out) {
  const int g = blockIdx.x * 256 + threadIdx.x;  // b*32+d
  const int d = g & 31;
  float A[32], G[32];
  #pragma unroll
  for (int k = 0; k < 32; ++k) {
    A[k] = drift_W[d * (H_ + D_) + H_ + k];
    G[k] = diff_W[d * (H_ + D_) + H_ + k];
  }
  float y = y0[g];
  const float fh = fhid[g], gh = ghid[g];
  out[g] = y;  // t=0 slice
  float dw0 = dW[g];
  float dw1 = dW[(size_t)(B_ * D_) + g];
  for (int t = 0; t < T_ - 1; ++t) {
    float dwn = 0.0f;
    if (t + 2 < T_ - 1) dwn = dW[(size_t)(t + 2) * (B_ * D_) + g];  // prefetch depth 2
    const float dt = ts[t + 1] - ts[t];
    const float sdt = sqrtf(dt);
    float f0 = 0.f, f1 = 0.f, f2 = 0.f, f3 = 0.f;
    float g0 = 0.f, g1 = 0.f, g2 = 0.f, g3 = 0.f;
    #pragma unroll
    for (int kq = 0; kq < 8; ++kq) {
      const float y0v = __shfl(y, kq * 4 + 0, 32);
      const float y1v = __shfl(y, kq * 4 + 1, 32);
      const float y2v = __shfl(y, kq * 4 + 2, 32);
      const float y3v = __shfl(y, kq * 4 + 3, 32);
      f0 += A[kq * 4 + 0] * y0v; g0 += G[kq * 4 + 0] * y0v;
      f1 += A[kq * 4 + 1] * y1v; g1 += G[kq * 4 + 1] * y1v;
      f2 += A[kq * 4 + 2] * y2v; g2 += G[kq * 4 + 2] * y2v;
      f3 += A[kq * 4 + 3] * y3v; g3 += G[kq * 4 + 3] * y3v;
    }
    const float f = fh + ((f0 + f1) + (f2 + f3));
    const float gg = gh + ((g0 + g1) + (g2 + g3));
    y = y + f * dt + gg * (dw0 * sdt);
    out[(size_t)(t + 1) * (B_ * D_) + g] = y;
    dw0 = dw1;
    dw1 = dwn;
  }
}

extern "C" void kernel_launch(void* const* d_in, const int* in_sizes, int n_in,
                              void* d_out, int out_size, void* d_ws, size_t ws_size,
                              hipStream_t stream) {
  const float* ts = (const float*)d_in[0];
  const float* y0 = (const float*)d_in[1];
  const float* xseq = (const float*)d_in[2];
  const float* dW = (const float*)d_in[3];
  const float* W_ih = (const float*)d_in[4];
  const float* W_hh = (const float*)d_in[5];
  const float* b_ih = (const float*)d_in[6];
  const float* b_hh = (const float*)d_in[7];
  const float* drift_W = (const float*)d_in[8];
  const float* drift_b = (const float*)d_in[9];
  const float* diff_W = (const float*)d_in[10];
  const float* diff_b = (const float*)d_in[11];
  float* out = (float*)d_out;

  char* p = (char*)d_ws;
  __hip_bfloat16* xT = (__hip_bfloat16*)p; p += (size_t)L_ * B_ * I_ * 2;  // 67.1 MB
  __hip_bfloat16* Wc = (__hip_bfloat16*)p; p += (size_t)NG * K_ * 2;       // 655 KB
  float* bc = (float*)p;                   p += (size_t)NG * 4;
  __hip_bfloat16* h0 = (__hip_bfloat16*)p; p += (size_t)B_ * H_ * 2;
  __hip_bfloat16* h1 = (__hip_bfloat16*)p; p += (size_t)B_ * H_ * 2;
  float* c = (float*)p;                    p += (size_t)B_ * H_ * 4;
  float* fh = (float*)p;                   p += (size_t)B_ * D_ * 4;
  float* gh = (float*)p;                   p += (size_t)B_ * D_ * 4;

  prep_w<<<(NG * K_ + 255) / 256, 256, 0, stream>>>(W_ih, W_hh, b_ih, b_hh, Wc, bc);
  prep_x<<<dim3(L_, B_ / 4), dim3(64, 4), 0, stream>>>(xseq, xT);
  prep_zero<<<(B_ * H_ + 255) / 256, 256, 0, stream>>>(h0, c);

  __hip_bfloat16* hb[2] = {h0, h1};
  for (int t = 0; t < L_; ++t) {
    lstm_step2<<<256, 512, 0, stream>>>(xT + (size_t)t * B_ * I_, hb[t & 1],
                                        hb[(t + 1) & 1], Wc, bc, c);
  }
  hid_proj<<<B_ / 8, 256, 0, stream>>>(hb[L_ & 1], drift_W, drift_b, diff_W, diff_b, fh, gh);
  sde_kernel<<<(B_ * D_) / 256, 256, 0, stream>>>(ts, y0, dW, drift_W, diff_W, fh, gh, out);
}